// Round 3
// baseline (529.903 us; speedup 1.0000x reference)
//
#include <hip/hip_runtime.h>
#include <math.h>

// ---------------------------------------------------------------------------
// VAE ELBO (chromatin VAE). Sizes fixed by the reference.
//
// Restructurings vs the JAX graph:
//  * NB_ENC == NB_DEC == 16, identical binning => ONE histogram serves both
//    the encoder input (log1p counts) and the mixture likelihood
//    (sum_{c,g,k} hist*(logits-lse) + N_CUTS*log 16).
//  * Histogram packed as u8 counters, 4 cells/u32 word (16 MB, L2-resident):
//    atomicAdd(word, 1<<8*(c&3)). Cell counts have mean 0.25, max ~10 --
//    byte overflow impossible. This keeps the 4M random atomics inside L2
//    (r2 profile: u32 hist = 64 MB > L2 => 125 MB HBM writeback, 154 us).
//  * enc_b1 cancels exactly through BatchNorm.
//  * log1p(n) for integer n == __logf(1+n) exactly.
//  * Decoder fused per (cell,gene); gene-per-block => weights wave-uniform.
//  * All sums -> one f64 accumulator; constants folded at finalize.
// ---------------------------------------------------------------------------

#define G_      1000
#define C_      1024
#define L_      50
#define K_      16
#define NHID_   16
#define CUT_SCALE   12.5f          // N_TOTAL_CUTS / N_CUTS
#define CELL_SCALE  9.765625f      // N_TOTAL_CELLS / N_CELLS

// ws layout (bytes). [0, ZERO_BYTES) is zeroed each call; latT fully written.
#define HIST_OFF 0ull              // u8  [16000][1024] packed 4 cells/word
#define FRAG_OFF 16384000ull       // u32 [1000][1024]   (g, c)
#define H_OFF    20480000ull       // f32 [16][1024]     hT (transposed, no b1)
#define BN_OFF   20545536ull       // f32 scale[16], shift[16]
#define ACC_OFF  20545664ull       // f64 [1]
#define ZERO_BYTES 20545672ull
#define LATT_OFF 20545672ull       // f32 [50][1024]     latent transposed
#define WS_BYTES 20750472ull

__device__ __forceinline__ float block_sum_256(float v) {
    __shared__ float sm[256];
    int t = threadIdx.x;
    __syncthreads();
    sm[t] = v;
    __syncthreads();
#pragma unroll
    for (int s = 128; s > 0; s >>= 1) {
        if (t < s) sm[t] += sm[t + s];
        __syncthreads();
    }
    return sm[0];
}

// --- 1. cut histogram: byte (g*16+b, c) += 1, packed 4 cells/word ----------
__global__ void hist_kernel(const float* __restrict__ coord,
                            const int* __restrict__ cxg,
                            unsigned int* __restrict__ histw, int n) {
    int i = blockIdx.x * 256 + threadIdx.x;
    if (i >= n) return;
    float x = coord[i];
    int b = (int)(x * 16.0f);
    b = b > 15 ? 15 : b;
    int ix = cxg[i];
    int c = ix / G_;
    int g = ix - c * G_;
    unsigned int word = (unsigned int)(g * K_ + b) * (C_ / 4) + (c >> 2);
    atomicAdd(&histw[word], 1u << ((c & 3) * 8));
}

// --- 2. fragment counts (transposed [g][c], u32, 4 MB = L2-resident) -------
__global__ void frag_kernel(const int* __restrict__ fix,
                            unsigned int* __restrict__ frag, int n) {
    int i = blockIdx.x * 256 + threadIdx.x;
    if (i >= n) return;
    int ix = fix[i];
    int c = ix / G_;
    int g = ix - c * G_;
    atomicAdd(&frag[(size_t)g * C_ + c], 1u);
}

// --- 3. encoder matmul: hT[j][c] = sum_i log1p(hist[i][c]) * W1[i][j] ------
// 250 blocks (64 i-rows each) x 256 threads; thread owns 4 cells (one word).
__global__ __launch_bounds__(256)
void enc_kernel(const unsigned int* __restrict__ histw, // [16000][256 words]
                const float* __restrict__ W1,           // [16000][16]
                float* __restrict__ hT) {               // [16][1024]
    int t = threadIdx.x;
    int i0 = blockIdx.x * 64;
    float acc[NHID_][4];
#pragma unroll
    for (int j = 0; j < NHID_; ++j)
#pragma unroll
        for (int u = 0; u < 4; ++u) acc[j][u] = 0.f;
    const unsigned int* hrow = histw + (size_t)i0 * (C_ / 4) + t;
    const float* w = W1 + (size_t)i0 * NHID_;
    for (int ii = 0; ii < 64; ++ii) {
        unsigned int cw = hrow[ii * (C_ / 4)];
        float x0 = __logf((float)((cw & 0xffu) + 1u));
        float x1 = __logf((float)(((cw >> 8) & 0xffu) + 1u));
        float x2 = __logf((float)(((cw >> 16) & 0xffu) + 1u));
        float x3 = __logf((float)((cw >> 24) + 1u));
        const float* wr = w + ii * NHID_;       // wave-uniform -> s_load
#pragma unroll
        for (int j = 0; j < NHID_; ++j) {
            float wj = wr[j];
            acc[j][0] = fmaf(x0, wj, acc[j][0]);
            acc[j][1] = fmaf(x1, wj, acc[j][1]);
            acc[j][2] = fmaf(x2, wj, acc[j][2]);
            acc[j][3] = fmaf(x3, wj, acc[j][3]);
        }
    }
#pragma unroll
    for (int j = 0; j < NHID_; ++j)
#pragma unroll
        for (int u = 0; u < 4; ++u)
            atomicAdd(&hT[j * C_ + 4 * t + u], acc[j][u]);
}

// --- 4. BN stats -> per-feature scale/shift --------------------------------
__global__ void bn_kernel(const float* __restrict__ hT,
                          const float* __restrict__ gamma,
                          const float* __restrict__ beta,
                          float* __restrict__ bn) {  // [0..15]=scale, [16..31]=shift
    int j = blockIdx.x;
    float s1 = 0.f, s2 = 0.f;
    for (int c = threadIdx.x; c < C_; c += 256) {
        float v = hT[j * C_ + c];
        s1 += v; s2 += v * v;
    }
    s1 = block_sum_256(s1);
    s2 = block_sum_256(s2);
    if (threadIdx.x == 0) {
        float mean = s1 * (1.0f / C_);
        float var = s2 * (1.0f / C_) - mean * mean;
        float rstd = rsqrtf(var + 1e-5f);
        float sc = gamma[j] * rstd;
        bn[j] = sc;
        bn[NHID_ + j] = beta[j] - mean * sc;
    }
}

// --- 5. latent sample + latent KL ------------------------------------------
__global__ __launch_bounds__(256)
void latent_kernel(const float* __restrict__ hT,
                   const float* __restrict__ bn,
                   const float* __restrict__ W_loc,   // [16][50]
                   const float* __restrict__ b_loc,
                   const float* __restrict__ W_scale, // [16][50]
                   const float* __restrict__ b_scale,
                   const float* __restrict__ eps,     // [1024][50]
                   float* __restrict__ latT,          // [50][1024]
                   double* __restrict__ acc) {
    int idx = blockIdx.x * 256 + threadIdx.x;
    float kl = 0.f;
    if (idx < C_ * L_) {
        int c = idx / L_;
        int l = idx - c * L_;
        float hb[NHID_];
#pragma unroll
        for (int j = 0; j < NHID_; ++j) {
            float v = fmaf(hT[j * C_ + c], bn[j], bn[NHID_ + j]);
            hb[j] = v > 0.f ? v : 0.f;
        }
        float loc = b_loc[l], ls = b_scale[l];
#pragma unroll
        for (int j = 0; j < NHID_; ++j) {
            loc = fmaf(hb[j], W_loc[j * L_ + l], loc);
            ls  = fmaf(hb[j], W_scale[j * L_ + l], ls);
        }
        float qs = 0.1f * __expf(ls);
        float e = eps[idx];
        float lat = fmaf(qs, e, loc);
        latT[(size_t)l * C_ + c] = lat;
        float z = (lat - loc) / qs;
        // logN(lat;0,1) - logN(lat;loc,qs) = -lat^2/2 + z^2/2 + log(qs)
        kl = fmaf(-0.5f * lat, lat, fmaf(0.5f * z, z, __logf(qs)));
    }
    float s = block_sum_256(kl);
    if (threadIdx.x == 0) atomicAdd(acc, -(double)(CELL_SCALE * s));
}

// --- 6. weight KL (logit_weight + rho_weight), N(0,0.1) --------------------
__global__ __launch_bounds__(256)
void wkl_kernel(const float* __restrict__ lw,  // 800000
                const float* __restrict__ rw,  // 50000
                double* __restrict__ acc) {
    const int NTOT = G_ * L_ * K_ + G_ * L_;   // 850000
    float s = 0.f;
    for (int i = blockIdx.x * 256 + threadIdx.x; i < NTOT; i += gridDim.x * 256) {
        float w = (i < G_ * L_ * K_) ? lw[i] : rw[i - G_ * L_ * K_];
        s += fmaf(-50.f * w, w, 1.3836465597893733f);
    }
    s = block_sum_256(s);
    if (threadIdx.x == 0) atomicAdd(acc, -(double)s);
}

// --- 7. fused decoder: mixture + Poisson likelihood per (c,g) --------------
// grid (1000 genes, 4 cell-tiles) x 256 threads
__global__ __launch_bounds__(256)
void main_kernel(const float* __restrict__ latT,        // [50][1024]
                 const unsigned int* __restrict__ histw,// [16000][256 words]
                 const unsigned int* __restrict__ frag, // [1000][1024]
                 const float* __restrict__ lw,          // [1000][50][16]
                 const float* __restrict__ rw,          // [1000][50]
                 const float* __restrict__ baseline,    // [1000][16]
                 const float* __restrict__ rho_bias,    // [1000]
                 const int* __restrict__ libsize,
                 double* __restrict__ acc) {
    int g = blockIdx.x;
    int c = blockIdx.y * 256 + threadIdx.x;
    const float* lwg = lw + (size_t)g * (L_ * K_);   // wave-uniform base
    const float* rwg = rw + (size_t)g * L_;
    float logits[K_];
#pragma unroll
    for (int k = 0; k < K_; ++k) logits[k] = baseline[g * K_ + k];
    float rho = 0.f;
    for (int l = 0; l < L_; ++l) {
        float lv = latT[(size_t)l * C_ + c];         // coalesced
        rho = fmaf(lv, rwg[l], rho);
#pragma unroll
        for (int k = 0; k < K_; ++k)
            logits[k] = fmaf(lv, lwg[l * K_ + k], logits[k]);  // s_load operand
    }
    float m = logits[0];
#pragma unroll
    for (int k = 1; k < K_; ++k) m = fmaxf(m, logits[k]);
    float se = 0.f;
#pragma unroll
    for (int k = 0; k < K_; ++k) se += __expf(logits[k] - m);
    float lse = m + __logf(se);
    float mix = 0.f;
    int sh = (c & 3) * 8;
#pragma unroll
    for (int k = 0; k < K_; ++k) {
        unsigned int cw = histw[(size_t)(g * K_ + k) * (C_ / 4) + (c >> 2)];
        float cnt = (float)((cw >> sh) & 0xffu);
        mix = fmaf(cnt, logits[k] - lse, mix);
    }
    float fc = (float)frag[(size_t)g * C_ + c];
    float fe = rho_bias[g] * __expf(rho) * (float)libsize[c];
    float lf = fmaf(fc, __logf(fe), -fe) - lgammaf(fc + 1.0f);
    float v = -(CUT_SCALE * mix + CELL_SCALE * lf);
    float s = block_sum_256(v);
    if (threadIdx.x == 0) atomicAdd(acc, (double)s);
}

// --- 8. finalize -----------------------------------------------------------
__global__ void final_kernel(const double* __restrict__ acc, float* __restrict__ out) {
    // -CUT_SCALE_total * log(16): 12.5 * 4e6 * log(16)
    out[0] = (float)(acc[0] - 138629436.11198905);
}

extern "C" void kernel_launch(void* const* d_in, const int* in_sizes, int n_in,
                              void* d_out, int out_size, void* d_ws, size_t ws_size,
                              hipStream_t stream) {
    const float* cut_coord = (const float*)d_in[0];
    const float* eps       = (const float*)d_in[1];
    const float* enc_W1    = (const float*)d_in[2];
    // d_in[3] = enc_b1 : cancels through BatchNorm, unused
    const float* bn_gamma  = (const float*)d_in[4];
    const float* bn_beta   = (const float*)d_in[5];
    const float* W_loc     = (const float*)d_in[6];
    const float* b_loc     = (const float*)d_in[7];
    const float* W_scale   = (const float*)d_in[8];
    const float* b_scale   = (const float*)d_in[9];
    const float* logit_w   = (const float*)d_in[10];
    const float* rho_w     = (const float*)d_in[11];
    const float* baseline  = (const float*)d_in[12];
    const float* rho_bias  = (const float*)d_in[13];
    const int* cut_cxg     = (const int*)d_in[14];
    // d_in[15] = cut_local_gene_ix : derivable from cxg, unused
    const int* frag_ix     = (const int*)d_in[16];
    // d_in[17] genes_oi, d_in[18] cells_oi : identity, unused
    const int* libsize     = (const int*)d_in[19];

    char* ws = (char*)d_ws;
    unsigned int* histw = (unsigned int*)(ws + HIST_OFF);
    unsigned int* frag  = (unsigned int*)(ws + FRAG_OFF);
    float* hT   = (float*)(ws + H_OFF);
    float* bn   = (float*)(ws + BN_OFF);
    double* acc = (double*)(ws + ACC_OFF);
    float* latT = (float*)(ws + LATT_OFF);
    float* out  = (float*)d_out;

    int n_cuts  = in_sizes[0];
    int n_frags = in_sizes[16];

    hipMemsetAsync(d_ws, 0, ZERO_BYTES, stream);

    hist_kernel<<<(n_cuts + 255) / 256, 256, 0, stream>>>(cut_coord, cut_cxg, histw, n_cuts);
    frag_kernel<<<(n_frags + 255) / 256, 256, 0, stream>>>(frag_ix, frag, n_frags);
    enc_kernel<<<250, 256, 0, stream>>>(histw, enc_W1, hT);
    bn_kernel<<<NHID_, 256, 0, stream>>>(hT, bn_gamma, bn_beta, bn);
    latent_kernel<<<(C_ * L_ + 255) / 256, 256, 0, stream>>>(
        hT, bn, W_loc, b_loc, W_scale, b_scale, eps, latT, acc);
    wkl_kernel<<<512, 256, 0, stream>>>(logit_w, rho_w, acc);
    main_kernel<<<dim3(G_, 4), 256, 0, stream>>>(
        latT, histw, frag, logit_w, rho_w, baseline, rho_bias, libsize, acc);
    final_kernel<<<1, 1, 0, stream>>>(acc, out);
}

// Round 4
// 515.029 us; speedup vs baseline: 1.0289x; 1.0289x over previous
//
#include <hip/hip_runtime.h>
#include <math.h>

// ---------------------------------------------------------------------------
// VAE ELBO (chromatin VAE). Sizes fixed by the reference.
//
//  * NB_ENC == NB_DEC == 16, identical binning => ONE histogram serves both
//    the encoder input (log1p counts) and the mixture likelihood.
//  * r3 lesson: device-scope atomics write through L2 (~32 B/atomic to the
//    coherent point; WRITE_SIZE == 32B x n_atomics regardless of footprint).
//    Fix: 8 per-XCD replicas selected by HW_REG_XCC_ID + WORKGROUP-scope
//    atomics => RMW executes in the XCD-local L2. Kernel-boundary release
//    flushes dirty L2, so the merge in the next kernel sees all updates.
//  * hist = 4-bit counters (8 cells/u32): P(count>=16) ~ 1e-16 at lambda=.25.
//    frag = u16 pairs. Replica merge = plain u32 adds (no cross-lane carry).
//  * enc fuses replica merge (writes merged nibble hist for main) and emits
//    per-chunk partials (NO float atomics); bn reduces partials; latent
//    derives BN scale/shift from f64 sums.
//  * All sums -> one f64 accumulator; N_CUTS*log(16) folded at finalize.
// ---------------------------------------------------------------------------

#define G_      1000
#define C_      1024
#define L_      50
#define K_      16
#define NHID_   16
#define CUT_SCALE   12.5f          // N_TOTAL_CUTS / N_CUTS
#define CELL_SCALE  9.765625f      // N_TOTAL_CELLS / N_CELLS

#define HWORDS_ 2048000u           // nibble hist words per replica (16000*128)
#define FWORDS_ 512000u            // u16 frag words per replica (1000*512)
#define NCHUNK_ 250                // encoder partial chunks

__device__ __forceinline__ unsigned int xcc_id() {
    unsigned int x;
    asm volatile("s_getreg_b32 %0, hwreg(HW_REG_XCC_ID, 0, 4)" : "=s"(x));
    return x & 7u;
}

__device__ __forceinline__ float block_sum_256(float v) {
    __shared__ float sm[256];
    int t = threadIdx.x;
    __syncthreads();
    sm[t] = v;
    __syncthreads();
#pragma unroll
    for (int s = 128; s > 0; s >>= 1) {
        if (t < s) sm[t] += sm[t + s];
        __syncthreads();
    }
    return sm[0];
}

// --- 1. cut histogram: nibble (g*16+b, c) += 1, per-XCD replica ------------
template<bool WG>
__global__ void hist_kernel(const float* __restrict__ coord,
                            const int* __restrict__ cxg,
                            unsigned int* __restrict__ histr, int n) {
    int i = blockIdx.x * 256 + threadIdx.x;
    if (i >= n) return;
    unsigned int* H = histr;
    if (WG) H += (size_t)xcc_id() * HWORDS_;
    float x = coord[i];
    int b = (int)(x * 16.0f);
    b = b > 15 ? 15 : b;
    int ix = cxg[i];
    int c = ix / G_;
    int g = ix - c * G_;
    unsigned int word = (unsigned int)(g * K_ + b) * (C_ / 8) + ((unsigned)c >> 3);
    unsigned int inc = 1u << ((c & 7) * 4);
    if (WG)
        __hip_atomic_fetch_add(&H[word], inc, __ATOMIC_RELAXED,
                               __HIP_MEMORY_SCOPE_WORKGROUP);
    else
        atomicAdd(&H[word], inc);
}

// --- 2. fragment counts: u16 (g, c) += 1, per-XCD replica ------------------
template<bool WG>
__global__ void frag_kernel(const int* __restrict__ fix,
                            unsigned int* __restrict__ fragr, int n) {
    int i = blockIdx.x * 256 + threadIdx.x;
    if (i >= n) return;
    unsigned int* F = fragr;
    if (WG) F += (size_t)xcc_id() * FWORDS_;
    int ix = fix[i];
    int c = ix / G_;
    int g = ix - c * G_;
    unsigned int word = ((unsigned int)(g * C_) + (unsigned)c) >> 1;
    unsigned int inc = 1u << ((c & 1) * 16);
    if (WG)
        __hip_atomic_fetch_add(&F[word], inc, __ATOMIC_RELAXED,
                               __HIP_MEMORY_SCOPE_WORKGROUP);
    else
        atomicAdd(&F[word], inc);
}

// --- 3. encoder: merge replicas + matmul partials --------------------------
// 125 blocks x 256 thr; thread: word w = t&127 (8 cells), row-lane rl = t>>7.
// Block covers 128 rows; writes merged hist + partial P[chunk][16][1024].
template<int NREP>
__global__ __launch_bounds__(256)
void enc_kernel(const unsigned int* __restrict__ histr,
                const float* __restrict__ W1,       // [16000][16]
                unsigned int* __restrict__ merged,  // [16000][128] nibble
                float* __restrict__ P) {            // [250][16][1024]
    int t = threadIdx.x;
    int w = t & 127;
    int rl = t >> 7;
    int row0 = blockIdx.x * 128;
    float acc[NHID_][8];
#pragma unroll
    for (int j = 0; j < NHID_; ++j)
#pragma unroll
        for (int u = 0; u < 8; ++u) acc[j][u] = 0.f;
    for (int it = 0; it < 64; ++it) {
        int row = row0 + it * 2 + rl;
        unsigned int idx = (unsigned)row * 128u + (unsigned)w;
        unsigned int mw = 0;
#pragma unroll
        for (int r = 0; r < NREP; ++r) mw += histr[(size_t)r * HWORDS_ + idx];
        merged[idx] = mw;
        float xv[8];
#pragma unroll
        for (int u = 0; u < 8; ++u)
            xv[u] = __logf((float)(((mw >> (u * 4)) & 0xfu) + 1u));
        const float* wr = W1 + (size_t)row * NHID_;   // wave-uniform -> s_load
#pragma unroll
        for (int j = 0; j < NHID_; ++j) {
            float wj = wr[j];
#pragma unroll
            for (int u = 0; u < 8; ++u) acc[j][u] = fmaf(xv[u], wj, acc[j][u]);
        }
    }
    float* Pp = P + (size_t)(blockIdx.x * 2 + rl) * (NHID_ * C_) + (w * 8);
#pragma unroll
    for (int j = 0; j < NHID_; ++j)
#pragma unroll
        for (int u = 0; u < 8; ++u) Pp[j * C_ + u] = acc[j][u];
}

// --- 4. reduce partials -> hT[j][c]; f64 BN sums ---------------------------
// grid (16 j, 4 cell-tiles) x 256
__global__ __launch_bounds__(256)
void bn_kernel(const float* __restrict__ P,
               float* __restrict__ hT,
               double* __restrict__ bnsum) {  // [0..15]=sum, [16..31]=sumsq
    int j = blockIdx.x;
    int c = blockIdx.y * 256 + threadIdx.x;
    float s = 0.f;
    for (int ch = 0; ch < NCHUNK_; ++ch)
        s += P[((size_t)ch * NHID_ + j) * C_ + c];
    hT[j * C_ + c] = s;
    float s1 = block_sum_256(s);
    float s2 = block_sum_256(s * s);
    if (threadIdx.x == 0) {
        atomicAdd(&bnsum[j], (double)s1);
        atomicAdd(&bnsum[NHID_ + j], (double)s2);
    }
}

// --- 5. latent sample + latent KL (BN scale/shift derived inline) ----------
__global__ __launch_bounds__(256)
void latent_kernel(const float* __restrict__ hT,
                   const double* __restrict__ bnsum,
                   const float* __restrict__ gamma,
                   const float* __restrict__ beta,
                   const float* __restrict__ W_loc,   // [16][50]
                   const float* __restrict__ b_loc,
                   const float* __restrict__ W_scale, // [16][50]
                   const float* __restrict__ b_scale,
                   const float* __restrict__ eps,     // [1024][50]
                   float* __restrict__ latT,          // [50][1024]
                   double* __restrict__ acc) {
    int idx = blockIdx.x * 256 + threadIdx.x;
    float kl = 0.f;
    if (idx < C_ * L_) {
        int c = idx / L_;
        int l = idx - c * L_;
        float hb[NHID_];
#pragma unroll
        for (int j = 0; j < NHID_; ++j) {
            float mean = (float)(bnsum[j] * (1.0 / C_));
            float ex2  = (float)(bnsum[NHID_ + j] * (1.0 / C_));
            float var = ex2 - mean * mean;
            float rstd = rsqrtf(var + 1e-5f);
            float sc = gamma[j] * rstd;
            float sh = beta[j] - mean * sc;
            float v = fmaf(hT[j * C_ + c], sc, sh);
            hb[j] = v > 0.f ? v : 0.f;
        }
        float loc = b_loc[l], ls = b_scale[l];
#pragma unroll
        for (int j = 0; j < NHID_; ++j) {
            loc = fmaf(hb[j], W_loc[j * L_ + l], loc);
            ls  = fmaf(hb[j], W_scale[j * L_ + l], ls);
        }
        float qs = 0.1f * __expf(ls);
        float e = eps[idx];
        float lat = fmaf(qs, e, loc);
        latT[(size_t)l * C_ + c] = lat;
        float z = (lat - loc) / qs;
        kl = fmaf(-0.5f * lat, lat, fmaf(0.5f * z, z, __logf(qs)));
    }
    float s = block_sum_256(kl);
    if (threadIdx.x == 0) atomicAdd(acc, -(double)(CELL_SCALE * s));
}

// --- 6. weight KL (logit_weight + rho_weight), N(0,0.1) --------------------
__global__ __launch_bounds__(256)
void wkl_kernel(const float* __restrict__ lw,  // 800000
                const float* __restrict__ rw,  // 50000
                double* __restrict__ acc) {
    const int NTOT = G_ * L_ * K_ + G_ * L_;   // 850000
    float s = 0.f;
    for (int i = blockIdx.x * 256 + threadIdx.x; i < NTOT; i += gridDim.x * 256) {
        float w = (i < G_ * L_ * K_) ? lw[i] : rw[i - G_ * L_ * K_];
        s += fmaf(-50.f * w, w, 1.3836465597893733f);
    }
    s = block_sum_256(s);
    if (threadIdx.x == 0) atomicAdd(acc, -(double)s);
}

// --- 7. fused decoder: mixture + Poisson likelihood per (c,g) --------------
// grid (1000 genes, 4 cell-tiles) x 256 threads
template<int NREP>
__global__ __launch_bounds__(256)
void main_kernel(const float* __restrict__ latT,         // [50][1024]
                 const unsigned int* __restrict__ merged,// nibble hist
                 const unsigned int* __restrict__ fragr, // u16 replicas
                 const float* __restrict__ lw,           // [1000][50][16]
                 const float* __restrict__ rw,           // [1000][50]
                 const float* __restrict__ baseline,     // [1000][16]
                 const float* __restrict__ rho_bias,     // [1000]
                 const int* __restrict__ libsize,
                 double* __restrict__ acc) {
    int g = blockIdx.x;
    int c = blockIdx.y * 256 + threadIdx.x;
    const float* lwg = lw + (size_t)g * (L_ * K_);   // wave-uniform base
    const float* rwg = rw + (size_t)g * L_;
    float logits[K_];
#pragma unroll
    for (int k = 0; k < K_; ++k) logits[k] = baseline[g * K_ + k];
    float rho = 0.f;
    for (int l = 0; l < L_; ++l) {
        float lv = latT[(size_t)l * C_ + c];         // coalesced
        rho = fmaf(lv, rwg[l], rho);
#pragma unroll
        for (int k = 0; k < K_; ++k)
            logits[k] = fmaf(lv, lwg[l * K_ + k], logits[k]);
    }
    float m = logits[0];
#pragma unroll
    for (int k = 1; k < K_; ++k) m = fmaxf(m, logits[k]);
    float se = 0.f;
#pragma unroll
    for (int k = 0; k < K_; ++k) se += __expf(logits[k] - m);
    float lse = m + __logf(se);
    float mix = 0.f;
    int sh4 = (c & 7) * 4;
#pragma unroll
    for (int k = 0; k < K_; ++k) {
        unsigned int cw = merged[(unsigned)(g * K_ + k) * (C_ / 8) + ((unsigned)c >> 3)];
        float cnt = (float)((cw >> sh4) & 0xfu);
        mix = fmaf(cnt, logits[k] - lse, mix);
    }
    unsigned int fw = ((unsigned)(g * C_) + (unsigned)c) >> 1;
    unsigned int fsh = (c & 1) * 16;
    unsigned int fcnt = 0;
#pragma unroll
    for (int r = 0; r < NREP; ++r)
        fcnt += (fragr[(size_t)r * FWORDS_ + fw] >> fsh) & 0xffffu;
    float fc = (float)fcnt;
    float fe = rho_bias[g] * __expf(rho) * (float)libsize[c];
    float lf = fmaf(fc, __logf(fe), -fe) - lgammaf(fc + 1.0f);
    float v = -(CUT_SCALE * mix + CELL_SCALE * lf);
    float s = block_sum_256(v);
    if (threadIdx.x == 0) atomicAdd(acc, (double)s);
}

// --- 8. finalize -----------------------------------------------------------
__global__ void final_kernel(const double* __restrict__ acc, float* __restrict__ out) {
    // -12.5 * 4e6 * log(16)
    out[0] = (float)(acc[0] - 138629436.11198905);
}

extern "C" void kernel_launch(void* const* d_in, const int* in_sizes, int n_in,
                              void* d_out, int out_size, void* d_ws, size_t ws_size,
                              hipStream_t stream) {
    const float* cut_coord = (const float*)d_in[0];
    const float* eps       = (const float*)d_in[1];
    const float* enc_W1    = (const float*)d_in[2];
    // d_in[3] = enc_b1 : cancels through BatchNorm, unused
    const float* bn_gamma  = (const float*)d_in[4];
    const float* bn_beta   = (const float*)d_in[5];
    const float* W_loc     = (const float*)d_in[6];
    const float* b_loc     = (const float*)d_in[7];
    const float* W_scale   = (const float*)d_in[8];
    const float* b_scale   = (const float*)d_in[9];
    const float* logit_w   = (const float*)d_in[10];
    const float* rho_w     = (const float*)d_in[11];
    const float* baseline  = (const float*)d_in[12];
    const float* rho_bias  = (const float*)d_in[13];
    const int* cut_cxg     = (const int*)d_in[14];
    const int* frag_ix     = (const int*)d_in[16];
    const int* libsize     = (const int*)d_in[19];

    int n_cuts  = in_sizes[0];
    int n_frags = in_sizes[16];

    // ws layout (nrep = 8 or fallback 1). Zeroed: replicas + acc + bnsum.
    auto need = [](size_t nrep) {
        return nrep * (8192000ull + 2048000ull) + 264ull      // reps+acc+bnsum
             + 8192000ull + 16384000ull + 65536ull + 204800ull; // merged,P,hT,latT
    };
    int nrep = (ws_size >= need(8)) ? 8 : 1;

    char* ws = (char*)d_ws;
    size_t histr_off  = 0;
    size_t fragr_off  = histr_off + (size_t)nrep * 8192000ull;
    size_t acc_off    = fragr_off + (size_t)nrep * 2048000ull;
    size_t bnsum_off  = acc_off + 8;
    size_t zero_end   = bnsum_off + 256;
    size_t merged_off = zero_end;
    size_t p_off      = merged_off + 8192000ull;
    size_t ht_off     = p_off + 16384000ull;
    size_t latt_off   = ht_off + 65536ull;

    unsigned int* histr  = (unsigned int*)(ws + histr_off);
    unsigned int* fragr  = (unsigned int*)(ws + fragr_off);
    double*       acc    = (double*)(ws + acc_off);
    double*       bnsum  = (double*)(ws + bnsum_off);
    unsigned int* merged = (unsigned int*)(ws + merged_off);
    float*        P      = (float*)(ws + p_off);
    float*        hT     = (float*)(ws + ht_off);
    float*        latT   = (float*)(ws + latt_off);
    float*        out    = (float*)d_out;

    hipMemsetAsync(ws, 0, zero_end, stream);

    if (nrep == 8) {
        hist_kernel<true><<<(n_cuts + 255) / 256, 256, 0, stream>>>(
            cut_coord, cut_cxg, histr, n_cuts);
        frag_kernel<true><<<(n_frags + 255) / 256, 256, 0, stream>>>(
            frag_ix, fragr, n_frags);
        enc_kernel<8><<<125, 256, 0, stream>>>(histr, enc_W1, merged, P);
    } else {
        hist_kernel<false><<<(n_cuts + 255) / 256, 256, 0, stream>>>(
            cut_coord, cut_cxg, histr, n_cuts);
        frag_kernel<false><<<(n_frags + 255) / 256, 256, 0, stream>>>(
            frag_ix, fragr, n_frags);
        enc_kernel<1><<<125, 256, 0, stream>>>(histr, enc_W1, merged, P);
    }
    bn_kernel<<<dim3(16, 4), 256, 0, stream>>>(P, hT, bnsum);
    latent_kernel<<<(C_ * L_ + 255) / 256, 256, 0, stream>>>(
        hT, bnsum, bn_gamma, bn_beta, W_loc, b_loc, W_scale, b_scale,
        eps, latT, acc);
    wkl_kernel<<<512, 256, 0, stream>>>(logit_w, rho_w, acc);
    if (nrep == 8)
        main_kernel<8><<<dim3(G_, 4), 256, 0, stream>>>(
            latT, merged, fragr, logit_w, rho_w, baseline, rho_bias, libsize, acc);
    else
        main_kernel<1><<<dim3(G_, 4), 256, 0, stream>>>(
            latT, merged, fragr, logit_w, rho_w, baseline, rho_bias, libsize, acc);
    final_kernel<<<1, 1, 0, stream>>>(acc, out);
}